// Round 1
// baseline (2844.944 us; speedup 1.0000x reference)
//
#include <hip/hip_runtime.h>

// LTC fused scan kernel for MI355X.
// B=512 batch rows, each handled by one 512-thread workgroup (8 waves).
// lane = unit index j (U=64). Waves split the i-reduction:
//   sensory: wave w owns i in [16w, 16w+16)   (I=128)
//   recurrent: wave w owns i in [8w, 8w+8)    (U=64)
// All per-synapse params live in registers (pre-transformed once):
//   z = sigma*(v - mu); sigmoid(z) = 1/(1+exp2(a*v + c)) with
//   a = -log2e*sigma, c = log2e*sigma*mu.  num uses softplus(w)*erev,
//   den uses softplus(w).
// Per-thread param storage = 4*(16+8) = 96 VGPRs -> fits in the 128-VGPR
// budget (8-wave blocks, 4 waves/SIMD resident), unlike the previous
// 4-wave layout whose 192 param values forced AGPR/scratch shuffling.
// Partial num/den exchanged via LDS, 1 barrier per unfold (4/t).

#define NB 512
#define NT 512
#define NI 128
#define NU 64
#define NO 15
#define L2E 1.44269504088896340736f

__device__ __forceinline__ float bcastf(float v, int lane) {
  return __int_as_float(__builtin_amdgcn_readlane(__float_as_int(v), lane));
}

__device__ __forceinline__ float wsum64(float x) {
#pragma unroll
  for (int m = 32; m >= 1; m >>= 1) x += __shfl_xor(x, m, 64);
  return x;
}

__device__ __forceinline__ float softplus_f(float x) {
  // matches jax.nn.softplus for our input range (x in [-0.2, 1])
  return log1pf(expf(x));
}

__device__ __forceinline__ float sigm_term(float a, float vb, float c) {
  // sigmoid(sigma*(v-mu)) with pre-folded a = -L2E*sigma, c = L2E*sigma*mu
  float z = fmaf(a, vb, c);
  float e = __builtin_amdgcn_exp2f(z);
  return __builtin_amdgcn_rcpf(1.0f + e);
}

__global__ __launch_bounds__(512, 4) void ltc_fused(
    const float* __restrict__ x,
    const float* __restrict__ input_w, const float* __restrict__ input_b,
    const float* __restrict__ sensory_w, const float* __restrict__ sensory_mu,
    const float* __restrict__ sensory_sigma, const float* __restrict__ sensory_erev,
    const float* __restrict__ w_, const float* __restrict__ mu_,
    const float* __restrict__ sigma_, const float* __restrict__ erev_,
    const float* __restrict__ gleak, const float* __restrict__ vleak,
    const float* __restrict__ cm,
    const float* __restrict__ output_w, const float* __restrict__ output_b,
    const float* __restrict__ ln_w, const float* __restrict__ ln_b,
    const float* __restrict__ fc_w, const float* __restrict__ fc_b,
    float* __restrict__ out)
{
  const int b    = blockIdx.x;
  const int tid  = threadIdx.x;
  const int wv   = tid >> 6;     // wave 0..7
  const int lane = tid & 63;     // unit j

  __shared__ float2 xbuf[4][8][NU];   // [unfold][wave][lane] partial (num,den)

  // ---- load + transform sensory params: i = 16*wv + k, j = lane ----
  float sa[16], sc[16], swe[16], swp[16];
#pragma unroll
  for (int k = 0; k < 16; ++k) {
    const int idx = (16 * wv + k) * NU + lane;
    const float ss = sensory_sigma[idx];
    const float sm = sensory_mu[idx];
    const float sw = softplus_f(sensory_w[idx]);
    const float se = sensory_erev[idx];
    sa[k]  = -L2E * ss;
    sc[k]  =  L2E * ss * sm;
    swe[k] = sw * se;
    swp[k] = sw;
  }
  // ---- recurrent params: i = 8*wv + k, j = lane ----
  float ra[8], rc[8], rwe[8], rwp[8];
#pragma unroll
  for (int k = 0; k < 8; ++k) {
    const int idx = (8 * wv + k) * NU + lane;
    const float sg = sigma_[idx];
    const float m  = mu_[idx];
    const float ww = softplus_f(w_[idx]);
    const float ev = erev_[idx];
    ra[k]  = -L2E * sg;
    rc[k]  =  L2E * sg * m;
    rwe[k] = ww * ev;
    rwp[k] = ww;
  }

  // ---- per-neuron constants (lane = j) ----
  const float glp   = softplus_f(gleak[lane]);
  const float cmt   = softplus_f(cm[lane]) * 4.0f;   // softplus(cm)/(1/UNFOLDS)
  const float glvl  = glp * vleak[lane];
  const float dbase = cmt + glp + 1e-8f;             // fold EPS in once

  // lane's sensory input index for the x-load (lanes 16..63 duplicate 0..15)
  const int ii = 16 * wv + (lane & 15);
  const float iw = input_w[ii];
  const float ib = input_b[ii];

  float v = 0.0f;
  const float* xp = x + (size_t)b * NT * NI + ii;
  float xv = xp[0];

#pragma unroll 1
  for (int t = 0; t < NT; ++t) {
    const int tn = (t + 1 < NT) ? (t + 1) : t;
    const float xv_next = xp[(size_t)tn * NI];   // prefetch next timestep
    const float inp = fmaf(xv, iw, ib);

    // ---- sensory sums over my 16 i's (4 independent chains for ILP) ----
    float ns0=0.f, ns1=0.f, ns2=0.f, ns3=0.f;
    float ds0=0.f, ds1=0.f, ds2=0.f, ds3=0.f;
#pragma unroll
    for (int k = 0; k < 16; k += 4) {
      { float s = sigm_term(sa[k+0], bcastf(inp, k+0), sc[k+0]);
        ns0 = fmaf(swe[k+0], s, ns0); ds0 = fmaf(swp[k+0], s, ds0); }
      { float s = sigm_term(sa[k+1], bcastf(inp, k+1), sc[k+1]);
        ns1 = fmaf(swe[k+1], s, ns1); ds1 = fmaf(swp[k+1], s, ds1); }
      { float s = sigm_term(sa[k+2], bcastf(inp, k+2), sc[k+2]);
        ns2 = fmaf(swe[k+2], s, ns2); ds2 = fmaf(swp[k+2], s, ds2); }
      { float s = sigm_term(sa[k+3], bcastf(inp, k+3), sc[k+3]);
        ns3 = fmaf(swe[k+3], s, ns3); ds3 = fmaf(swp[k+3], s, ds3); }
    }
    const float wns = (ns0 + ns1) + (ns2 + ns3);
    const float wds = (ds0 + ds1) + (ds2 + ds3);

    // ---- 4 ODE unfolds ----
#pragma unroll
    for (int u = 0; u < 4; ++u) {
      float rn0=0.f, rn1=0.f, rn2=0.f, rn3=0.f;
      float rd0=0.f, rd1=0.f, rd2=0.f, rd3=0.f;
      const int i0 = 8 * wv;
#pragma unroll
      for (int k = 0; k < 8; k += 4) {
        { float s = sigm_term(ra[k+0], bcastf(v, i0+k+0), rc[k+0]);
          rn0 = fmaf(rwe[k+0], s, rn0); rd0 = fmaf(rwp[k+0], s, rd0); }
        { float s = sigm_term(ra[k+1], bcastf(v, i0+k+1), rc[k+1]);
          rn1 = fmaf(rwe[k+1], s, rn1); rd1 = fmaf(rwp[k+1], s, rd1); }
        { float s = sigm_term(ra[k+2], bcastf(v, i0+k+2), rc[k+2]);
          rn2 = fmaf(rwe[k+2], s, rn2); rd2 = fmaf(rwp[k+2], s, rd2); }
        { float s = sigm_term(ra[k+3], bcastf(v, i0+k+3), rc[k+3]);
          rn3 = fmaf(rwe[k+3], s, rn3); rd3 = fmaf(rwp[k+3], s, rd3); }
      }
      // fold my sensory partial into my exchanged partial
      const float np = ((rn0 + rn1) + (rn2 + rn3)) + wns;
      const float dp = ((rd0 + rd1) + (rd2 + rd3)) + wds;
      xbuf[u][wv][lane] = make_float2(np, dp);
      __syncthreads();
      // all 8 waves read all 8 partials in the same order -> identical v copies
      const float2 p0 = xbuf[u][0][lane];
      const float2 p1 = xbuf[u][1][lane];
      const float2 p2 = xbuf[u][2][lane];
      const float2 p3 = xbuf[u][3][lane];
      const float2 p4 = xbuf[u][4][lane];
      const float2 p5 = xbuf[u][5][lane];
      const float2 p6 = xbuf[u][6][lane];
      const float2 p7 = xbuf[u][7][lane];
      const float sn = ((p0.x + p1.x) + (p2.x + p3.x)) + ((p4.x + p5.x) + (p6.x + p7.x));
      const float sd = ((p0.y + p1.y) + (p2.y + p3.y)) + ((p4.y + p5.y) + (p6.y + p7.y));
      const float num = fmaf(cmt, v, glvl) + sn;
      const float den = dbase + sd;
      v = num * __builtin_amdgcn_rcpf(den);
      // note: next write to xbuf[u] is 4 barriers away -> no WAR hazard
    }
    xv = xv_next;
  }

  // ---- head: affine out-map, LayerNorm(eps=1e-5), fc (O=15) ----
  if (wv == 0) {
    const float h    = fmaf(v, output_w[lane], output_b[lane]);
    const float mean = wsum64(h) * (1.0f / 64.0f);
    const float d    = h - mean;
    const float var  = wsum64(d * d) * (1.0f / 64.0f);
    const float hn   = d * rsqrtf(var + 1e-5f) * ln_w[lane] + ln_b[lane];
#pragma unroll
    for (int o = 0; o < NO; ++o) {
      const float p = wsum64(hn * fc_w[o * NU + lane]);
      if (lane == 0) out[b * NO + o] = p + fc_b[o];
    }
  }
}

extern "C" void kernel_launch(void* const* d_in, const int* in_sizes, int n_in,
                              void* d_out, int out_size, void* d_ws, size_t ws_size,
                              hipStream_t stream) {
  const float* x             = (const float*)d_in[0];
  const float* input_w       = (const float*)d_in[1];
  const float* input_b       = (const float*)d_in[2];
  const float* sensory_w     = (const float*)d_in[3];
  const float* sensory_mu    = (const float*)d_in[4];
  const float* sensory_sigma = (const float*)d_in[5];
  const float* sensory_erev  = (const float*)d_in[6];
  const float* w_            = (const float*)d_in[7];
  const float* mu_           = (const float*)d_in[8];
  const float* sigma_        = (const float*)d_in[9];
  const float* erev_         = (const float*)d_in[10];
  const float* gleak         = (const float*)d_in[11];
  const float* vleak         = (const float*)d_in[12];
  const float* cm            = (const float*)d_in[13];
  const float* output_w      = (const float*)d_in[14];
  const float* output_b      = (const float*)d_in[15];
  const float* ln_w          = (const float*)d_in[16];
  const float* ln_b          = (const float*)d_in[17];
  const float* fc_w          = (const float*)d_in[18];
  const float* fc_b          = (const float*)d_in[19];
  float* out = (float*)d_out;

  ltc_fused<<<dim3(NB), dim3(512), 0, stream>>>(
      x, input_w, input_b, sensory_w, sensory_mu, sensory_sigma, sensory_erev,
      w_, mu_, sigma_, erev_, gleak, vleak, cm, output_w, output_b,
      ln_w, ln_b, fc_w, fc_b, out);
}

// Round 2
// 2691.577 us; speedup vs baseline: 1.0570x; 1.0570x over previous
//
#include <hip/hip_runtime.h>

// LTC fused scan kernel for MI355X.
// B=512 batch rows, each handled by one 512-thread workgroup (8 waves).
// lane = unit index j (U=64). Waves split the i-reduction:
//   sensory: wave w owns i in [16w, 16w+16)   (I=128)
//   recurrent: wave w owns i in [8w, 8w+8)    (U=64)
// All per-synapse params live in registers (pre-transformed once):
//   z = sigma*(v - mu); sigmoid(z) = 1/(1+exp2(a*v + c)) with
//   a = -log2e*sigma, c = log2e*sigma*mu.
// Register trick: erev is exactly +-1, so softplus(w)*erev (numerator
// weight) carries the denominator weight as its magnitude. We store only
// swe = softplus(w)*erev and use fmaf(fabsf(swe), ...) for the
// denominator -- the abs() is a free VOP3 input modifier on gfx950.
// Param storage: 3*(16+8) = 72 VGPRs/thread -> fits the
// __launch_bounds__(512,4) budget without scratch (round-1 version
// stored 96 and spilled 90 B/thread to scratch: WRITE_SIZE 1.6->23.6 MB).
// Partial num/den exchanged via LDS, 1 barrier per unfold (4/t).

#define NB 512
#define NT 512
#define NI 128
#define NU 64
#define NO 15
#define L2E 1.44269504088896340736f

__device__ __forceinline__ float bcastf(float v, int lane) {
  return __int_as_float(__builtin_amdgcn_readlane(__float_as_int(v), lane));
}

__device__ __forceinline__ float wsum64(float x) {
#pragma unroll
  for (int m = 32; m >= 1; m >>= 1) x += __shfl_xor(x, m, 64);
  return x;
}

__device__ __forceinline__ float softplus_f(float x) {
  // matches jax.nn.softplus for our input range (x in [-0.2, 1])
  return log1pf(expf(x));
}

__device__ __forceinline__ float sigm_term(float a, float vb, float c) {
  // sigmoid(sigma*(v-mu)) with pre-folded a = -L2E*sigma, c = L2E*sigma*mu
  float z = fmaf(a, vb, c);
  float e = __builtin_amdgcn_exp2f(z);
  return __builtin_amdgcn_rcpf(1.0f + e);
}

__global__ __launch_bounds__(512, 4) void ltc_fused(
    const float* __restrict__ x,
    const float* __restrict__ input_w, const float* __restrict__ input_b,
    const float* __restrict__ sensory_w, const float* __restrict__ sensory_mu,
    const float* __restrict__ sensory_sigma, const float* __restrict__ sensory_erev,
    const float* __restrict__ w_, const float* __restrict__ mu_,
    const float* __restrict__ sigma_, const float* __restrict__ erev_,
    const float* __restrict__ gleak, const float* __restrict__ vleak,
    const float* __restrict__ cm,
    const float* __restrict__ output_w, const float* __restrict__ output_b,
    const float* __restrict__ ln_w, const float* __restrict__ ln_b,
    const float* __restrict__ fc_w, const float* __restrict__ fc_b,
    float* __restrict__ out)
{
  const int b    = blockIdx.x;
  const int tid  = threadIdx.x;
  const int wv   = tid >> 6;     // wave 0..7
  const int lane = tid & 63;     // unit j

  __shared__ float2 xbuf[4][8][NU];   // [unfold][wave][lane] partial (num,den)

  // ---- load + transform sensory params: i = 16*wv + k, j = lane ----
  float sa[16], sc[16], swe[16];
#pragma unroll
  for (int k = 0; k < 16; ++k) {
    const int idx = (16 * wv + k) * NU + lane;
    const float ss = sensory_sigma[idx];
    const float sm = sensory_mu[idx];
    const float sw = softplus_f(sensory_w[idx]);
    const float se = sensory_erev[idx];
    sa[k]  = -L2E * ss;
    sc[k]  =  L2E * ss * sm;
    swe[k] = sw * se;                 // |swe| == softplus(w), since se = +-1
  }
  // ---- recurrent params: i = 8*wv + k, j = lane ----
  float ra[8], rc[8], rwe[8];
#pragma unroll
  for (int k = 0; k < 8; ++k) {
    const int idx = (8 * wv + k) * NU + lane;
    const float sg = sigma_[idx];
    const float m  = mu_[idx];
    const float ww = softplus_f(w_[idx]);
    const float ev = erev_[idx];
    ra[k]  = -L2E * sg;
    rc[k]  =  L2E * sg * m;
    rwe[k] = ww * ev;                 // |rwe| == softplus(w)
  }

  // ---- per-neuron constants (lane = j) ----
  const float glp   = softplus_f(gleak[lane]);
  const float cmt   = softplus_f(cm[lane]) * 4.0f;   // softplus(cm)/(1/UNFOLDS)
  const float glvl  = glp * vleak[lane];
  const float dbase = cmt + glp + 1e-8f;             // fold EPS in once

  // lane's sensory input index for the x-load (lanes 16..63 duplicate 0..15)
  const int ii = 16 * wv + (lane & 15);
  const float iw = input_w[ii];
  const float ib = input_b[ii];

  float v = 0.0f;
  const float* xp = x + (size_t)b * NT * NI + ii;
  float xv = xp[0];

#pragma unroll 1
  for (int t = 0; t < NT; ++t) {
    const int tn = (t + 1 < NT) ? (t + 1) : t;
    const float xv_next = xp[(size_t)tn * NI];   // prefetch next timestep
    const float inp = fmaf(xv, iw, ib);

    // ---- sensory sums over my 16 i's (4 independent chains for ILP) ----
    float ns0=0.f, ns1=0.f, ns2=0.f, ns3=0.f;
    float ds0=0.f, ds1=0.f, ds2=0.f, ds3=0.f;
#pragma unroll
    for (int k = 0; k < 16; k += 4) {
      { float s = sigm_term(sa[k+0], bcastf(inp, k+0), sc[k+0]);
        ns0 = fmaf(swe[k+0], s, ns0); ds0 = fmaf(fabsf(swe[k+0]), s, ds0); }
      { float s = sigm_term(sa[k+1], bcastf(inp, k+1), sc[k+1]);
        ns1 = fmaf(swe[k+1], s, ns1); ds1 = fmaf(fabsf(swe[k+1]), s, ds1); }
      { float s = sigm_term(sa[k+2], bcastf(inp, k+2), sc[k+2]);
        ns2 = fmaf(swe[k+2], s, ns2); ds2 = fmaf(fabsf(swe[k+2]), s, ds2); }
      { float s = sigm_term(sa[k+3], bcastf(inp, k+3), sc[k+3]);
        ns3 = fmaf(swe[k+3], s, ns3); ds3 = fmaf(fabsf(swe[k+3]), s, ds3); }
    }
    const float wns = (ns0 + ns1) + (ns2 + ns3);
    const float wds = (ds0 + ds1) + (ds2 + ds3);

    // ---- 4 ODE unfolds ----
#pragma unroll
    for (int u = 0; u < 4; ++u) {
      float rn0=0.f, rn1=0.f, rn2=0.f, rn3=0.f;
      float rd0=0.f, rd1=0.f, rd2=0.f, rd3=0.f;
      const int i0 = 8 * wv;
#pragma unroll
      for (int k = 0; k < 8; k += 4) {
        { float s = sigm_term(ra[k+0], bcastf(v, i0+k+0), rc[k+0]);
          rn0 = fmaf(rwe[k+0], s, rn0); rd0 = fmaf(fabsf(rwe[k+0]), s, rd0); }
        { float s = sigm_term(ra[k+1], bcastf(v, i0+k+1), rc[k+1]);
          rn1 = fmaf(rwe[k+1], s, rn1); rd1 = fmaf(fabsf(rwe[k+1]), s, rd1); }
        { float s = sigm_term(ra[k+2], bcastf(v, i0+k+2), rc[k+2]);
          rn2 = fmaf(rwe[k+2], s, rn2); rd2 = fmaf(fabsf(rwe[k+2]), s, rd2); }
        { float s = sigm_term(ra[k+3], bcastf(v, i0+k+3), rc[k+3]);
          rn3 = fmaf(rwe[k+3], s, rn3); rd3 = fmaf(fabsf(rwe[k+3]), s, rd3); }
      }
      // fold my sensory partial into my exchanged partial
      const float np = ((rn0 + rn1) + (rn2 + rn3)) + wns;
      const float dp = ((rd0 + rd1) + (rd2 + rd3)) + wds;
      xbuf[u][wv][lane] = make_float2(np, dp);
      __syncthreads();
      // all 8 waves read all 8 partials in the same order -> identical v copies
      const float2 p0 = xbuf[u][0][lane];
      const float2 p1 = xbuf[u][1][lane];
      const float2 p2 = xbuf[u][2][lane];
      const float2 p3 = xbuf[u][3][lane];
      const float2 p4 = xbuf[u][4][lane];
      const float2 p5 = xbuf[u][5][lane];
      const float2 p6 = xbuf[u][6][lane];
      const float2 p7 = xbuf[u][7][lane];
      const float sn = ((p0.x + p1.x) + (p2.x + p3.x)) + ((p4.x + p5.x) + (p6.x + p7.x));
      const float sd = ((p0.y + p1.y) + (p2.y + p3.y)) + ((p4.y + p5.y) + (p6.y + p7.y));
      const float num = fmaf(cmt, v, glvl) + sn;
      const float den = dbase + sd;
      v = num * __builtin_amdgcn_rcpf(den);
      // note: next write to xbuf[u] is 4 barriers away -> no WAR hazard
    }
    xv = xv_next;
  }

  // ---- head: affine out-map, LayerNorm(eps=1e-5), fc (O=15) ----
  if (wv == 0) {
    const float h    = fmaf(v, output_w[lane], output_b[lane]);
    const float mean = wsum64(h) * (1.0f / 64.0f);
    const float d    = h - mean;
    const float var  = wsum64(d * d) * (1.0f / 64.0f);
    const float hn   = d * rsqrtf(var + 1e-5f) * ln_w[lane] + ln_b[lane];
#pragma unroll
    for (int o = 0; o < NO; ++o) {
      const float p = wsum64(hn * fc_w[o * NU + lane]);
      if (lane == 0) out[b * NO + o] = p + fc_b[o];
    }
  }
}

extern "C" void kernel_launch(void* const* d_in, const int* in_sizes, int n_in,
                              void* d_out, int out_size, void* d_ws, size_t ws_size,
                              hipStream_t stream) {
  const float* x             = (const float*)d_in[0];
  const float* input_w       = (const float*)d_in[1];
  const float* input_b       = (const float*)d_in[2];
  const float* sensory_w     = (const float*)d_in[3];
  const float* sensory_mu    = (const float*)d_in[4];
  const float* sensory_sigma = (const float*)d_in[5];
  const float* sensory_erev  = (const float*)d_in[6];
  const float* w_            = (const float*)d_in[7];
  const float* mu_           = (const float*)d_in[8];
  const float* sigma_        = (const float*)d_in[9];
  const float* erev_         = (const float*)d_in[10];
  const float* gleak         = (const float*)d_in[11];
  const float* vleak         = (const float*)d_in[12];
  const float* cm            = (const float*)d_in[13];
  const float* output_w      = (const float*)d_in[14];
  const float* output_b      = (const float*)d_in[15];
  const float* ln_w          = (const float*)d_in[16];
  const float* ln_b          = (const float*)d_in[17];
  const float* fc_w          = (const float*)d_in[18];
  const float* fc_b          = (const float*)d_in[19];
  float* out = (float*)d_out;

  ltc_fused<<<dim3(NB), dim3(512), 0, stream>>>(
      x, input_w, input_b, sensory_w, sensory_mu, sensory_sigma, sensory_erev,
      w_, mu_, sigma_, erev_, gleak, vleak, cm, output_w, output_b,
      ln_w, ln_b, fc_w, fc_b, out);
}

// Round 3
// 2121.041 us; speedup vs baseline: 1.3413x; 1.2690x over previous
//
#include <hip/hip_runtime.h>

// LTC fused scan kernel for MI355X.
// B=512 batch rows, each handled by one 256-thread workgroup (4 waves).
// lane = unit index j (U=64). Waves split the i-reduction:
//   sensory: wave w owns i in [32w, 32w+32)   (I=128)
//   recurrent: wave w owns i in [16w, 16w+16) (U=64)
// All per-synapse params live in registers (pre-transformed once):
//   z = sigma*(v - mu); sigmoid(z) = 1/(1+exp2(a*v + c)) with
//   a = -log2e*sigma, c = log2e*sigma*mu.
// Register trick: erev is exactly +-1, so softplus(w)*erev (numerator
// weight) carries the denominator weight as its magnitude: we store only
// swe = softplus(w)*erev and accumulate the denominator with
// fmaf(fabsf(swe), ...) -- abs() is a free VOP3 input modifier.
// Param storage: 3*(32+16) = 144 VGPRs/thread. __launch_bounds__(256, 1)
// raises the arch-VGPR cap to 256 so params + working set (~200) live
// entirely in arch VGPRs: no AGPR shuffling (round-0 pathology at cap
// 128) and no scratch spill (rounds 1-2 pathology at cap 64).
// Occupancy target: 2 blocks/CU (8 waves/CU), same residency as round 0.
// Partial num/den exchanged via LDS, 1 barrier per unfold (4/t).

#define NB 512
#define NT 512
#define NI 128
#define NU 64
#define NO 15
#define L2E 1.44269504088896340736f

__device__ __forceinline__ float bcastf(float v, int lane) {
  return __int_as_float(__builtin_amdgcn_readlane(__float_as_int(v), lane));
}

__device__ __forceinline__ float wsum64(float x) {
#pragma unroll
  for (int m = 32; m >= 1; m >>= 1) x += __shfl_xor(x, m, 64);
  return x;
}

__device__ __forceinline__ float softplus_f(float x) {
  // matches jax.nn.softplus for our input range (x in [-0.2, 1])
  return log1pf(expf(x));
}

__device__ __forceinline__ float sigm_term(float a, float vb, float c) {
  // sigmoid(sigma*(v-mu)) with pre-folded a = -L2E*sigma, c = L2E*sigma*mu
  float z = fmaf(a, vb, c);
  float e = __builtin_amdgcn_exp2f(z);
  return __builtin_amdgcn_rcpf(1.0f + e);
}

__global__ __launch_bounds__(256, 1) void ltc_fused(
    const float* __restrict__ x,
    const float* __restrict__ input_w, const float* __restrict__ input_b,
    const float* __restrict__ sensory_w, const float* __restrict__ sensory_mu,
    const float* __restrict__ sensory_sigma, const float* __restrict__ sensory_erev,
    const float* __restrict__ w_, const float* __restrict__ mu_,
    const float* __restrict__ sigma_, const float* __restrict__ erev_,
    const float* __restrict__ gleak, const float* __restrict__ vleak,
    const float* __restrict__ cm,
    const float* __restrict__ output_w, const float* __restrict__ output_b,
    const float* __restrict__ ln_w, const float* __restrict__ ln_b,
    const float* __restrict__ fc_w, const float* __restrict__ fc_b,
    float* __restrict__ out)
{
  const int b    = blockIdx.x;
  const int tid  = threadIdx.x;
  const int wv   = tid >> 6;     // wave 0..3
  const int lane = tid & 63;     // unit j

  __shared__ float2 xbuf[4][4][NU];   // [unfold][wave][lane] partial (num,den)

  // ---- load + transform sensory params: i = 32*wv + k, j = lane ----
  float sa[32], sc[32], swe[32];
#pragma unroll
  for (int k = 0; k < 32; ++k) {
    const int idx = (32 * wv + k) * NU + lane;
    const float ss = sensory_sigma[idx];
    const float sm = sensory_mu[idx];
    const float sw = softplus_f(sensory_w[idx]);
    const float se = sensory_erev[idx];
    sa[k]  = -L2E * ss;
    sc[k]  =  L2E * ss * sm;
    swe[k] = sw * se;                 // |swe| == softplus(w), since se = +-1
  }
  // ---- recurrent params: i = 16*wv + k, j = lane ----
  float ra[16], rc[16], rwe[16];
#pragma unroll
  for (int k = 0; k < 16; ++k) {
    const int idx = (16 * wv + k) * NU + lane;
    const float sg = sigma_[idx];
    const float m  = mu_[idx];
    const float ww = softplus_f(w_[idx]);
    const float ev = erev_[idx];
    ra[k]  = -L2E * sg;
    rc[k]  =  L2E * sg * m;
    rwe[k] = ww * ev;                 // |rwe| == softplus(w)
  }

  // ---- per-neuron constants (lane = j) ----
  const float glp   = softplus_f(gleak[lane]);
  const float cmt   = softplus_f(cm[lane]) * 4.0f;   // softplus(cm)/(1/UNFOLDS)
  const float glvl  = glp * vleak[lane];
  const float dbase = cmt + glp + 1e-8f;             // fold EPS in once

  // lane's sensory input index for the x-load (lanes 32..63 duplicate 0..31)
  const int ii = 32 * wv + (lane & 31);
  const float iw = input_w[ii];
  const float ib = input_b[ii];

  float v = 0.0f;
  const float* xp = x + (size_t)b * NT * NI + ii;
  float xv = xp[0];

#pragma unroll 1
  for (int t = 0; t < NT; ++t) {
    const int tn = (t + 1 < NT) ? (t + 1) : t;
    const float xv_next = xp[(size_t)tn * NI];   // prefetch next timestep
    const float inp = fmaf(xv, iw, ib);

    // ---- sensory sums over my 32 i's (4 independent chains for ILP) ----
    float ns0=0.f, ns1=0.f, ns2=0.f, ns3=0.f;
    float ds0=0.f, ds1=0.f, ds2=0.f, ds3=0.f;
#pragma unroll
    for (int k = 0; k < 32; k += 4) {
      { float s = sigm_term(sa[k+0], bcastf(inp, k+0), sc[k+0]);
        ns0 = fmaf(swe[k+0], s, ns0); ds0 = fmaf(fabsf(swe[k+0]), s, ds0); }
      { float s = sigm_term(sa[k+1], bcastf(inp, k+1), sc[k+1]);
        ns1 = fmaf(swe[k+1], s, ns1); ds1 = fmaf(fabsf(swe[k+1]), s, ds1); }
      { float s = sigm_term(sa[k+2], bcastf(inp, k+2), sc[k+2]);
        ns2 = fmaf(swe[k+2], s, ns2); ds2 = fmaf(fabsf(swe[k+2]), s, ds2); }
      { float s = sigm_term(sa[k+3], bcastf(inp, k+3), sc[k+3]);
        ns3 = fmaf(swe[k+3], s, ns3); ds3 = fmaf(fabsf(swe[k+3]), s, ds3); }
    }
    const float wns = (ns0 + ns1) + (ns2 + ns3);
    const float wds = (ds0 + ds1) + (ds2 + ds3);

    // ---- 4 ODE unfolds ----
#pragma unroll
    for (int u = 0; u < 4; ++u) {
      float rn0=0.f, rn1=0.f, rn2=0.f, rn3=0.f;
      float rd0=0.f, rd1=0.f, rd2=0.f, rd3=0.f;
      const int i0 = 16 * wv;
#pragma unroll
      for (int k = 0; k < 16; k += 4) {
        { float s = sigm_term(ra[k+0], bcastf(v, i0+k+0), rc[k+0]);
          rn0 = fmaf(rwe[k+0], s, rn0); rd0 = fmaf(fabsf(rwe[k+0]), s, rd0); }
        { float s = sigm_term(ra[k+1], bcastf(v, i0+k+1), rc[k+1]);
          rn1 = fmaf(rwe[k+1], s, rn1); rd1 = fmaf(fabsf(rwe[k+1]), s, rd1); }
        { float s = sigm_term(ra[k+2], bcastf(v, i0+k+2), rc[k+2]);
          rn2 = fmaf(rwe[k+2], s, rn2); rd2 = fmaf(fabsf(rwe[k+2]), s, rd2); }
        { float s = sigm_term(ra[k+3], bcastf(v, i0+k+3), rc[k+3]);
          rn3 = fmaf(rwe[k+3], s, rn3); rd3 = fmaf(fabsf(rwe[k+3]), s, rd3); }
      }
      // fold my sensory partial into my exchanged partial
      const float np = ((rn0 + rn1) + (rn2 + rn3)) + wns;
      const float dp = ((rd0 + rd1) + (rd2 + rd3)) + wds;
      xbuf[u][wv][lane] = make_float2(np, dp);
      __syncthreads();
      // all 4 waves read all 4 partials in the same order -> identical v copies
      const float2 p0 = xbuf[u][0][lane];
      const float2 p1 = xbuf[u][1][lane];
      const float2 p2 = xbuf[u][2][lane];
      const float2 p3 = xbuf[u][3][lane];
      const float num = fmaf(cmt, v, glvl) + ((p0.x + p1.x) + (p2.x + p3.x));
      const float den = dbase + ((p0.y + p1.y) + (p2.y + p3.y));
      v = num * __builtin_amdgcn_rcpf(den);
      // note: next write to xbuf[u] is 4 barriers away -> no WAR hazard
    }
    xv = xv_next;
  }

  // ---- head: affine out-map, LayerNorm(eps=1e-5), fc (O=15) ----
  if (wv == 0) {
    const float h    = fmaf(v, output_w[lane], output_b[lane]);
    const float mean = wsum64(h) * (1.0f / 64.0f);
    const float d    = h - mean;
    const float var  = wsum64(d * d) * (1.0f / 64.0f);
    const float hn   = d * rsqrtf(var + 1e-5f) * ln_w[lane] + ln_b[lane];
#pragma unroll
    for (int o = 0; o < NO; ++o) {
      const float p = wsum64(hn * fc_w[o * NU + lane]);
      if (lane == 0) out[b * NO + o] = p + fc_b[o];
    }
  }
}

extern "C" void kernel_launch(void* const* d_in, const int* in_sizes, int n_in,
                              void* d_out, int out_size, void* d_ws, size_t ws_size,
                              hipStream_t stream) {
  const float* x             = (const float*)d_in[0];
  const float* input_w       = (const float*)d_in[1];
  const float* input_b       = (const float*)d_in[2];
  const float* sensory_w     = (const float*)d_in[3];
  const float* sensory_mu    = (const float*)d_in[4];
  const float* sensory_sigma = (const float*)d_in[5];
  const float* sensory_erev  = (const float*)d_in[6];
  const float* w_            = (const float*)d_in[7];
  const float* mu_           = (const float*)d_in[8];
  const float* sigma_        = (const float*)d_in[9];
  const float* erev_         = (const float*)d_in[10];
  const float* gleak         = (const float*)d_in[11];
  const float* vleak         = (const float*)d_in[12];
  const float* cm            = (const float*)d_in[13];
  const float* output_w      = (const float*)d_in[14];
  const float* output_b      = (const float*)d_in[15];
  const float* ln_w          = (const float*)d_in[16];
  const float* ln_b          = (const float*)d_in[17];
  const float* fc_w          = (const float*)d_in[18];
  const float* fc_b          = (const float*)d_in[19];
  float* out = (float*)d_out;

  ltc_fused<<<dim3(NB), dim3(256), 0, stream>>>(
      x, input_w, input_b, sensory_w, sensory_mu, sensory_sigma, sensory_erev,
      w_, mu_, sigma_, erev_, gleak, vleak, cm, output_w, output_b,
      ln_w, ln_b, fc_w, fc_b, out);
}